// Round 5
// baseline (5905.790 us; speedup 1.0000x reference)
//
#include <hip/hip_runtime.h>

// RNN: S=512, B=128, I=256, H=512, O=128
// R5: fully AGPR-resident W_hh via 2-CU column split per batch group.
//  16 blocks (g = bid&7 batch rows g*16..+16, s = bid>>3 hidden half).
//  Wave w owns 64 hidden cols -> 4 ntiles x 16 kt = 64 frags = 256 AGPRs.
//  Per step: own-half h frags via small LDS transpose; remote half read
//  DIRECTLY from partner's hs store (row-major => contiguous dwordx4 frags).
//  Sync: per-block flag, agent-scope fences (cross-XCD safe).
//  hs[t] own half overwrites the xh[t] sub-region this CU consumed.

typedef __attribute__((ext_vector_type(8))) short short8;   // 8 bf16
typedef __attribute__((ext_vector_type(4))) float f32x4;    // MFMA C/D
typedef __attribute__((ext_vector_type(2))) unsigned int uint2v;

__device__ __forceinline__ unsigned short f32_to_bf16(float f) {
  unsigned int u = __float_as_uint(f);
  u += 0x7FFFu + ((u >> 16) & 1u);
  return (unsigned short)(u >> 16);
}
__device__ __forceinline__ float bf16lo_to_f32(unsigned u) {
  return __uint_as_float(u << 16);
}
__device__ __forceinline__ float bf16hi_to_f32(unsigned u) {
  return __uint_as_float(u & 0xFFFF0000u);
}
__device__ __forceinline__ float fast_tanh(float x) {
  float e = __expf(2.0f * x);
  return 1.0f - 2.0f / (e + 1.0f);
}

// ---------------------------------------------------------------------------
// Pack K x N fp32 row-major -> bf16 MFMA fragment tiles.
// Tile (nt,kt): lane holds W[k=kt*32+(lane>>4)*8+j][n=nt*16+(lane&15)],
// stored P[tile*512 + lane*8 + j], tile = nt*(K/32)+kt.
// ---------------------------------------------------------------------------
__global__ void pack_b_kernel(const float* __restrict__ W,
                              unsigned short* __restrict__ P, int K, int N) {
  int tid  = blockIdx.x * 256 + threadIdx.x;
  int lane = tid & 63;
  int tile = tid >> 6;
  int nKt  = K >> 5;
  int nTiles = (N >> 4) * nKt;
  if (tile >= nTiles) return;
  int nt = tile / nKt;
  int kt = tile - nt * nKt;
  int n  = (nt << 4) + (lane & 15);
  int k0 = (kt << 5) + ((lane >> 4) << 3);
  unsigned short* dst = P + (size_t)tile * 512 + lane * 8;
#pragma unroll
  for (int j = 0; j < 8; ++j)
    dst[j] = f32_to_bf16(W[(size_t)(k0 + j) * N + n]);
}

// ---------------------------------------------------------------------------
// Phase 1: xh = x@W_xh + b_h, swapped-operand MFMA; stored pre-swizzled:
// xh_s[(t*8+g)*8192 + by*2048 + lane*32 + nt*4 + r] =
//   xh[t][g*16 + (lane&15)][by*128 + nt*16 + (lane>>4)*4 + r]
// ---------------------------------------------------------------------------
__global__ __launch_bounds__(256) void xh_gemm_kernel(
    const float* __restrict__ x, const unsigned short* __restrict__ Wxh_p,
    const float* __restrict__ b_h, unsigned short* __restrict__ xh_s) {
  __shared__ __align__(16) unsigned short Abuf[64 * 264];
  const int tid = threadIdx.x;
  const int m0 = blockIdx.x * 64;

#pragma unroll
  for (int i = 0; i < 16; ++i) {
    int flat = i * 1024 + tid * 4;
    int row = flat >> 8, col = flat & 255;
    float4 v = *(const float4*)(x + (size_t)(m0 + row) * 256 + col);
    ushort4 u;
    u.x = f32_to_bf16(v.x); u.y = f32_to_bf16(v.y);
    u.z = f32_to_bf16(v.z); u.w = f32_to_bf16(v.w);
    *(ushort4*)(Abuf + row * 264 + col) = u;
  }
  __syncthreads();

  const int w2 = tid >> 6, lane = tid & 63;
  const int quad = lane >> 4, col16 = lane & 15;
  const int aBase = (w2 * 16 + col16) * 264 + quad * 8;
  const int t = (m0 + w2 * 16) >> 7;
  const int g = ((m0 + w2 * 16) & 127) >> 4;

  for (int by = 0; by < 4; ++by) {
    f32x4 acc[8];
#pragma unroll
    for (int nt = 0; nt < 8; ++nt) acc[nt] = (f32x4){0.f,0.f,0.f,0.f};
#pragma unroll
    for (int kt = 0; kt < 8; ++kt) {
      short8 xfrag = *(const short8*)(Abuf + aBase + kt * 32);
#pragma unroll
      for (int nt = 0; nt < 8; ++nt) {
        int tile = (by * 8 + nt) * 8 + kt;      // nKt(Wxh)=8
        short8 wfrag = *(const short8*)(Wxh_p + (size_t)tile * 512 + lane * 8);
        acc[nt] = __builtin_amdgcn_mfma_f32_16x16x32_bf16(wfrag, xfrag, acc[nt], 0, 0, 0);
      }
    }
    unsigned short hv[32];
#pragma unroll
    for (int nt = 0; nt < 8; ++nt) {
      float4 bh4 = *(const float4*)(b_h + by * 128 + nt * 16 + quad * 4);
#pragma unroll
      for (int r = 0; r < 4; ++r)
        hv[nt * 4 + r] = f32_to_bf16(acc[nt][r] + (&bh4.x)[r]);
    }
    unsigned short* dst = xh_s + ((size_t)(t * 8 + g) * 4 + by) * 2048 + lane * 32;
#pragma unroll
    for (int k = 0; k < 4; ++k) {
      uint4 u;
      u.x = (unsigned)hv[k*8+0] | ((unsigned)hv[k*8+1] << 16);
      u.y = (unsigned)hv[k*8+2] | ((unsigned)hv[k*8+3] << 16);
      u.z = (unsigned)hv[k*8+4] | ((unsigned)hv[k*8+5] << 16);
      u.w = (unsigned)hv[k*8+6] | ((unsigned)hv[k*8+7] << 16);
      *(uint4*)(dst + k * 8) = u;
    }
  }
}

// ---------------------------------------------------------------------------
// Phase 2: recurrence. grid 16, block 256. Block (g = bid&7, s = bid>>3).
// Partner block = bid ^ 8 (other hidden half, same batch group).
// hs[t] layout per (t,g) region of 8192 elems: half s at s*4096 + row*256+c.
// ---------------------------------------------------------------------------
__global__ __launch_bounds__(256, 1) void rnn_recurrence_kernel(
    const unsigned short* __restrict__ Whh_p,
    unsigned short* __restrict__ xhs,            // xh in, hs out (in-place)
    unsigned int* __restrict__ flags) {          // [16], zeroed by host memset
  __shared__ __align__(16) unsigned short Hb[2][16 * 264];   // own half only
  const int tid = threadIdx.x;
  const int w = tid >> 6, lane = tid & 63;
  const int quad = lane >> 4, col16 = lane & 15;
  const int bid = blockIdx.x;
  const int g = bid & 7, s = bid >> 3;
  const int partner = bid ^ 8;

  for (int i = tid; i < 2 * 16 * 264; i += 256) (&Hb[0][0])[i] = 0;

  // 64 W_hh frags -> AGPRs (exactly 256). Wave w owns global ntiles
  // ntg = s*16 + w*4 + ntL, all 16 kt. wf[kt*4 + ntL].
  short8 wf[64];
#pragma unroll
  for (int kt = 0; kt < 16; ++kt)
#pragma unroll
    for (int ntL = 0; ntL < 4; ++ntL) {
      int ntg = s * 16 + w * 4 + ntL;
      wf[kt * 4 + ntL] = *(const short8*)(
          Whh_p + ((size_t)(ntg * 16 + kt)) * 512 + lane * 8);
    }
#pragma unroll
  for (int f = 0; f < 64; ++f) asm volatile("" : "+a"(wf[f]));
  __syncthreads();

  const int by = s * 2 + (w >> 1);
  const unsigned short* xhL =
      xhs + (size_t)g * 8192 + (size_t)by * 2048 + lane * 32 + (w & 1) * 16;
  // hs store base (own half): region + s*4096 + row*256 + col_in_half
  unsigned short* hsW = xhs + (size_t)g * 8192 + (size_t)s * 4096 +
                        col16 * 256 + w * 64 + quad * 4;
  // remote frag base: region + (1-s)*4096 + col16*256 + kt''*32 + quad*8
  const unsigned short* rmB = xhs + (size_t)g * 8192 + (size_t)(1 - s) * 4096 +
                              col16 * 256 + quad * 8;
  const int aOwn = col16 * 264 + quad * 8;       // own-half frag base in Hb
  const int wbB  = col16 * 264 + w * 64 + quad * 4;  // epilogue write base
  const int ktOwn0 = s * 8, ktRem0 = (1 - s) * 8;

#pragma unroll 1
  for (int t = 0; t < 512; ++t) {
    const size_t reg = (size_t)t * 65536;        // region stride 8*8192

    // xh loads first (separated from partner's hs[t] writes by the barrier
    // below -- in-place aliasing is race-free).
    uint4 xq0 = *(const uint4*)(xhL + reg);
    uint4 xq1 = *(const uint4*)(xhL + reg + 8);

    short8 rf[8];
    if (t > 0) {
      if (tid == 0) {
        while (__hip_atomic_load(&flags[partner], __ATOMIC_RELAXED,
                                 __HIP_MEMORY_SCOPE_AGENT) < (unsigned)t)
          __builtin_amdgcn_s_sleep(1);
      }
      __syncthreads();
      __builtin_amdgcn_fence(__ATOMIC_ACQUIRE, "agent");
      const unsigned short* rp = rmB + reg - 65536;   // hs[t-1] remote half
#pragma unroll
      for (int k = 0; k < 8; ++k)
        rf[k] = *(const short8*)(rp + k * 32);
    } else {
      __syncthreads();
#pragma unroll
      for (int k = 0; k < 8; ++k) rf[k] = (short8){0,0,0,0,0,0,0,0};
    }

    f32x4 acc[4];
#pragma unroll
    for (int ntL = 0; ntL < 4; ++ntL) acc[ntL] = (f32x4){0.f,0.f,0.f,0.f};

    // Own-half kts from LDS (while remote loads are in flight).
    const unsigned short* rb = Hb[t & 1];
#pragma unroll
    for (int k = 0; k < 8; ++k) {
      short8 h = *(const short8*)(rb + aOwn + k * 32);
#pragma unroll
      for (int ntL = 0; ntL < 4; ++ntL)
        acc[ntL] = __builtin_amdgcn_mfma_f32_16x16x32_bf16(
            wf[(ktOwn0 + k) * 4 + ntL], h, acc[ntL], 0, 0, 0);
    }
    // Remote-half kts from registers.
#pragma unroll
    for (int k = 0; k < 8; ++k) {
#pragma unroll
      for (int ntL = 0; ntL < 4; ++ntL)
        acc[ntL] = __builtin_amdgcn_mfma_f32_16x16x32_bf16(
            wf[(ktRem0 + k) * 4 + ntL], rf[k], acc[ntL], 0, 0, 0);
    }

    // Epilogue: h_t = tanh(xh + acc); acc[ntL][r] covers
    // [row=col16][col = s*256 + w*64 + ntL*16 + quad*4 + r].
    unsigned xw[8] = {xq0.x, xq0.y, xq0.z, xq0.w, xq1.x, xq1.y, xq1.z, xq1.w};
    unsigned short* wb = Hb[(t & 1) ^ 1];
#pragma unroll
    for (int ntL = 0; ntL < 4; ++ntL) {
      float h0 = fast_tanh(acc[ntL][0] + bf16lo_to_f32(xw[ntL * 2]));
      float h1 = fast_tanh(acc[ntL][1] + bf16hi_to_f32(xw[ntL * 2]));
      float h2 = fast_tanh(acc[ntL][2] + bf16lo_to_f32(xw[ntL * 2 + 1]));
      float h3 = fast_tanh(acc[ntL][3] + bf16hi_to_f32(xw[ntL * 2 + 1]));
      uint2v o;
      o.x = (unsigned)f32_to_bf16(h0) | ((unsigned)f32_to_bf16(h1) << 16);
      o.y = (unsigned)f32_to_bf16(h2) | ((unsigned)f32_to_bf16(h3) << 16);
      *(uint2v*)(wb + wbB + ntL * 16) = o;       // LDS (next step's own half)
      *(uint2v*)(hsW + reg + ntL * 16) = o;      // global hs[t] (exchange+out)
    }

    __builtin_amdgcn_fence(__ATOMIC_RELEASE, "agent");
    __syncthreads();
    if (tid == 0)
      __hip_atomic_store(&flags[bid], (unsigned)(t + 1), __ATOMIC_RELAXED,
                         __HIP_MEMORY_SCOPE_AGENT);
  }
}

// ---------------------------------------------------------------------------
// Phase 3: out = hs @ W_hy + b_y.  hs layout: region(t,g)=(t*8+g)*8192,
// element h[t][g*16+row][k] at region + (k>>8)*4096 + row*256 + (k&255).
// ---------------------------------------------------------------------------
__global__ __launch_bounds__(256) void out_gemm_kernel(
    const unsigned short* __restrict__ hs, const unsigned short* __restrict__ Why_p,
    const float* __restrict__ b_y, float* __restrict__ out) {
  const int tid = threadIdx.x;
  const int w = tid >> 6, lane = tid & 63;
  const int quad = lane >> 4, col16 = lane & 15;
  const int m0 = blockIdx.x * 64 + w * 16;
  const size_t region = (size_t)((m0 >> 7) * 8 + ((m0 >> 4) & 7)) * 8192;

  f32x4 acc[8];
#pragma unroll
  for (int nt = 0; nt < 8; ++nt) acc[nt] = (f32x4){0.f,0.f,0.f,0.f};

  const unsigned short* aP = hs + region + col16 * 256 + quad * 8;
#pragma unroll
  for (int kt = 0; kt < 16; ++kt) {
    short8 a = *(const short8*)(aP + (kt >> 3) * 4096 + (kt & 7) * 32);
#pragma unroll
    for (int nt = 0; nt < 8; ++nt) {
      int tile = nt * 16 + kt;                 // nKt(Why)=16
      short8 b = *(const short8*)(Why_p + (size_t)tile * 512 + lane * 8);
      acc[nt] = __builtin_amdgcn_mfma_f32_16x16x32_bf16(a, b, acc[nt], 0, 0, 0);
    }
  }
#pragma unroll
  for (int nt = 0; nt < 8; ++nt) {
    int n = nt * 16 + col16;
    float by = b_y[n];
#pragma unroll
    for (int r = 0; r < 4; ++r)
      out[(size_t)(m0 + quad * 4 + r) * 128 + n] = acc[nt][r] + by;
  }
}

// ---------------------------------------------------------------------------
extern "C" void kernel_launch(void* const* d_in, const int* in_sizes, int n_in,
                              void* d_out, int out_size, void* d_ws, size_t ws_size,
                              hipStream_t stream) {
  const float* x    = (const float*)d_in[0];   // [512,128,256]
  const float* W_xh = (const float*)d_in[1];   // [256,512]
  const float* W_hh = (const float*)d_in[2];   // [512,512]
  const float* W_hy = (const float*)d_in[3];   // [512,128]
  const float* b_h  = (const float*)d_in[4];   // [512]
  const float* b_y  = (const float*)d_in[5];   // [128]
  float* out = (float*)d_out;                  // [512,128,128]

  char* ws = (char*)d_ws;
  unsigned short* Wxh_p = (unsigned short*)(ws);                 // 256 KB
  unsigned short* Whh_p = (unsigned short*)(ws + (256 << 10));   // 512 KB
  unsigned short* Why_p = (unsigned short*)(ws + (768 << 10));   // 128 KB
  unsigned int*   flags = (unsigned int*)(ws + (896 << 10));     // 64 B
  unsigned short* xhs   = (unsigned short*)(ws + (1024 << 10));  // 64 MB

  hipMemsetAsync(flags, 0, 16 * sizeof(unsigned int), stream);

  pack_b_kernel<<<64, 256, 0, stream>>>(W_xh, Wxh_p, 256, 512);
  pack_b_kernel<<<128, 256, 0, stream>>>(W_hh, Whh_p, 512, 512);
  pack_b_kernel<<<32, 256, 0, stream>>>(W_hy, Why_p, 512, 128);

  xh_gemm_kernel<<<1024, 256, 0, stream>>>(x, Wxh_p, b_h, xhs);

  rnn_recurrence_kernel<<<16, 256, 0, stream>>>(Whh_p, xhs, flags);

  out_gemm_kernel<<<1024, 256, 0, stream>>>(xhs, Why_p, b_y, out);
}